// Round 1
// baseline (756.708 us; speedup 1.0000x reference)
//
#include <hip/hip_runtime.h>

// ---------------------------------------------------------------------------
// Problem constants (from reference): B=8192, FD=1024, H=16, D=64,
// SCALES={64,128,256,512,1024} (sum 1984), S=5, LW=3, C=1000, GD=512.
//
// Restructuring:
//   K_j = sf_j @ (Wk@Ws_j)^T + ck_j   (fold scale proj into K/V weights)
//   V_j = sf_j @ (Wv@Ws_j)^T + cv_j
//   scale_importance via Gram trick: ||sum_w a_w V_w||^2 = a^T G a
// All big GEMMs in bf16 MFMA (16x16x32), f32 accumulate.
// ---------------------------------------------------------------------------

typedef short s16x8 __attribute__((ext_vector_type(8)));
typedef float f32x4 __attribute__((ext_vector_type(4)));

__device__ __forceinline__ ushort f2b(float x) {
  unsigned u = __float_as_uint(x);
  return (ushort)((u + 0x7fffu + ((u >> 16) & 1u)) >> 16);  // RNE
}
__device__ __forceinline__ float b2f(ushort u) {
  return __uint_as_float(((unsigned)u) << 16);
}

// ---------------- GEMM: C[M,N] = X[M,K] @ W[N,K]^T (+ bias[N]) --------------
// bf16 inputs (as ushort), 128x128 tile, BK=64, 4 waves each 64x64 (4x4 MFMA).
// LDS chunk xor-swizzle: chunk(16B) at slot s of row r holds global chunk s^(r&7)
// -> fragment ds_read_b128 is <=2-way bank aliased (free).
template <int OUT_BF16>
__global__ __launch_bounds__(256, 2) void gemm_xwt(
    const ushort* __restrict__ X, int ldx, const ushort* __restrict__ W, int ldw,
    void* __restrict__ Cv, int ldo, const float* __restrict__ bias,
    int M, int N, int K)
{
  __shared__ __align__(16) ushort As[128 * 64];
  __shared__ __align__(16) ushort Bs[128 * 64];
  const int tid = threadIdx.x;
  const int bm = blockIdx.x << 7, bn = blockIdx.y << 7;
  const int wave = tid >> 6, lane = tid & 63;
  const int wm = (wave >> 1) << 6, wn = (wave & 1) << 6;
  const int quad = lane >> 4, l16 = lane & 15;

  f32x4 acc[4][4];
  const f32x4 zero = {0.f, 0.f, 0.f, 0.f};
#pragma unroll
  for (int i = 0; i < 4; ++i)
#pragma unroll
    for (int j = 0; j < 4; ++j) acc[i][j] = zero;

  const int ktiles = K >> 6;
  for (int kt = 0; kt < ktiles; ++kt) {
    const int kbase = kt << 6;
    __syncthreads();
#pragma unroll
    for (int i = 0; i < 4; ++i) {
      int flat = (i << 8) + tid;          // 0..1023 chunk id (16B chunks)
      int row = flat >> 3, slot = flat & 7;
      int c = slot ^ (row & 7);
      int gr = bm + row; gr = (gr < M) ? gr : (M - 1);
      int4 v = *(const int4*)(X + (size_t)gr * ldx + kbase + (c << 3));
      *(int4*)(As + ((size_t)flat << 3)) = v;
    }
#pragma unroll
    for (int i = 0; i < 4; ++i) {
      int flat = (i << 8) + tid;
      int row = flat >> 3, slot = flat & 7;
      int c = slot ^ (row & 7);
      int gr = bn + row; gr = (gr < N) ? gr : (N - 1);
      int4 v = *(const int4*)(W + (size_t)gr * ldw + kbase + (c << 3));
      *(int4*)(Bs + ((size_t)flat << 3)) = v;
    }
    __syncthreads();
#pragma unroll
    for (int k0 = 0; k0 < 2; ++k0) {
      s16x8 af[4], bfr[4];
#pragma unroll
      for (int t = 0; t < 4; ++t) {
        int row = wm + (t << 4) + l16;
        int slot = ((k0 << 2) + quad) ^ (row & 7);
        af[t] = *(const s16x8*)(As + ((row << 3) + slot) * 8);
      }
#pragma unroll
      for (int t = 0; t < 4; ++t) {
        int row = wn + (t << 4) + l16;
        int slot = ((k0 << 2) + quad) ^ (row & 7);
        bfr[t] = *(const s16x8*)(Bs + ((row << 3) + slot) * 8);
      }
#pragma unroll
      for (int i = 0; i < 4; ++i)
#pragma unroll
        for (int j = 0; j < 4; ++j)
          acc[i][j] = __builtin_amdgcn_mfma_f32_16x16x32_bf16(af[i], bfr[j], acc[i][j], 0, 0, 0);
    }
  }

  // C/D layout: col = lane&15, row = quad*4 + reg   [measured m89/m91]
#pragma unroll
  for (int j = 0; j < 4; ++j) {
    int gn = bn + wn + (j << 4) + l16;
    if (gn < N) {
      float bv = bias ? bias[gn] : 0.f;
#pragma unroll
      for (int i = 0; i < 4; ++i) {
#pragma unroll
        for (int r = 0; r < 4; ++r) {
          int gm = bm + wm + (i << 4) + (quad << 2) + r;
          if (gm < M) {
            float val = acc[i][j][r] + bv;
            if (OUT_BF16) ((ushort*)Cv)[(size_t)gm * ldo + gn] = f2b(val);
            else          ((float*)Cv)[(size_t)gm * ldo + gn] = val;
          }
        }
      }
    }
  }
}

// ---------------- prep: per-row f32->bf16 of features + concat sf ----------
__global__ __launch_bounds__(256) void prep_rows(
    const float* __restrict__ feat,
    const float* __restrict__ s0, const float* __restrict__ s1,
    const float* __restrict__ s2, const float* __restrict__ s3,
    const float* __restrict__ s4,
    ushort* __restrict__ featb, ushort* __restrict__ sfc)
{
  int b = blockIdx.x, t = threadIdx.x;
  {
    float4 v = ((const float4*)(feat + (size_t)b * 1024))[t];
    ushort4 o; o.x = f2b(v.x); o.y = f2b(v.y); o.z = f2b(v.z); o.w = f2b(v.w);
    ((ushort4*)(featb + (size_t)b * 1024))[t] = o;
  }
  for (int c = t; c < 496; c += 256) {   // 496 float4 chunks per 1984-row
    int e = c << 2;
    const float* src;
    if (e < 64)        src = s0 + (size_t)b * 64 + e;
    else if (e < 192)  src = s1 + (size_t)b * 128 + (e - 64);
    else if (e < 448)  src = s2 + (size_t)b * 256 + (e - 192);
    else if (e < 960)  src = s3 + (size_t)b * 512 + (e - 448);
    else               src = s4 + (size_t)b * 1024 + (e - 960);
    float4 v = *(const float4*)src;
    ushort4 o; o.x = f2b(v.x); o.y = f2b(v.y); o.z = f2b(v.z); o.w = f2b(v.w);
    ((ushort4*)(sfc + (size_t)b * 1984))[c] = o;
  }
}

__device__ __forceinline__ void cvt4(const float* __restrict__ s, int si_,
                                     ushort* __restrict__ d, int di) {
  float4 v = ((const float4*)s)[si_];
  ushort4 o; o.x = f2b(v.x); o.y = f2b(v.y); o.z = f2b(v.z); o.w = f2b(v.w);
  ((ushort4*)d)[di] = o;
}

// ---------------- prep: weights to bf16, bias concats ----------------------
__global__ __launch_bounds__(256) void prep_w(
    const float* __restrict__ Wq, const float* __restrict__ Wg1,
    const float* __restrict__ Wk, const float* __restrict__ Wv,
    const float* __restrict__ bs, const float* __restrict__ semb,
    const float* __restrict__ bk, const float* __restrict__ bv,
    const float* __restrict__ bq, const float* __restrict__ bg1,
    ushort* __restrict__ Wqh, ushort* __restrict__ Wkvb,
    ushort* __restrict__ bse, float* __restrict__ bkv, float* __restrict__ bqg1)
{
  int id = blockIdx.x * 256 + threadIdx.x;   // float4-chunk id
  if (id < 262144) { cvt4(Wq, id, Wqh, id); return; }
  id -= 262144;
  if (id < 131072) { cvt4(Wg1, id, Wqh + 1048576, id); return; }
  id -= 131072;
  if (id < 262144) { cvt4(Wk, id, Wkvb, id); return; }
  id -= 262144;
  if (id < 262144) { cvt4(Wv, id, Wkvb + 1048576, id); return; }
  id -= 262144;
  if (id < 1280) {   // bse = (bs + scale_emb) -> bf16, [5][1024]
    float4 a = ((const float4*)bs)[id];
    float4 b = ((const float4*)semb)[id];
    ushort4 o; o.x = f2b(a.x + b.x); o.y = f2b(a.y + b.y);
    o.z = f2b(a.z + b.z); o.w = f2b(a.w + b.w);
    ((ushort4*)bse)[id] = o;
    return;
  }
  id -= 1280;
  if (id < 512) {    // bkv = concat(bk, bv) f32 [2048]
    float4 v = (id < 256) ? ((const float4*)bk)[id] : ((const float4*)bv)[id - 256];
    ((float4*)bkv)[id] = v;
    return;
  }
  id -= 512;
  if (id < 384) {    // bqg1 = concat(bq, bg1) f32 [1536]
    float4 v = (id < 256) ? ((const float4*)bq)[id] : ((const float4*)bg1)[id - 256];
    ((float4*)bqg1)[id] = v;
  }
}

// ---------------- prep: WsT[off_j+k][c] = Ws_j[c][k]  (f32 -> bf16) --------
__global__ __launch_bounds__(256) void transpose_ws(
    const float* __restrict__ Ws0, const float* __restrict__ Ws1,
    const float* __restrict__ Ws2, const float* __restrict__ Ws3,
    const float* __restrict__ Ws4, ushort* __restrict__ WsT)
{
  __shared__ float tile[64][65];
  int kt = blockIdx.x, ct = blockIdx.y;
  const float* Ws; int kb, scj, offj;
  if (kt < 1)       { Ws = Ws0; kb = kt;      scj = 64;   offj = 0;   }
  else if (kt < 3)  { Ws = Ws1; kb = kt - 1;  scj = 128;  offj = 64;  }
  else if (kt < 7)  { Ws = Ws2; kb = kt - 3;  scj = 256;  offj = 192; }
  else if (kt < 15) { Ws = Ws3; kb = kt - 7;  scj = 512;  offj = 448; }
  else              { Ws = Ws4; kb = kt - 15; scj = 1024; offj = 960; }
  int c0 = ct << 6, k0 = kb << 6;
  int col = threadIdx.x & 63, r4 = threadIdx.x >> 6;
#pragma unroll
  for (int p = 0; p < 16; ++p) {
    int r = (p << 2) + r4;
    tile[r][col] = Ws[(size_t)(c0 + r) * scj + k0 + col];
  }
  __syncthreads();
#pragma unroll
  for (int p = 0; p < 16; ++p) {
    int r = (p << 2) + r4;
    WsT[(size_t)(offj + k0 + r) * 1024 + c0 + col] = f2b(tile[col][r]);
  }
}

// ---------------- attention reduction -> scale_importance ------------------
// One wave per row b. Per head h: 5 Q.K dots + 15 V-Gram dots via butterfly.
// Then softmax over 3 routed scales and  si = mean_h sqrt(a^T G a).
__global__ __launch_bounds__(256) void attn_si_kernel(
    const ushort* __restrict__ QH, const ushort* __restrict__ KV,
    const int* __restrict__ routes, const float* __restrict__ temp,
    float* __restrict__ si)
{
  int wave = threadIdx.x >> 6, lane = threadIdx.x & 63;
  int b = (blockIdx.x << 2) + wave;
  __shared__ float red[4][16][20];
  const ushort* q = QH + (size_t)b * 1536;
  const ushort* kv = KV + (size_t)b * 10240;

  for (int h = 0; h < 16; ++h) {
    float qv = b2f(q[h * 64 + lane]);
    float kk[5], vv[5];
#pragma unroll
    for (int j = 0; j < 5; ++j) {
      kk[j] = b2f(kv[j * 2048 + h * 64 + lane]);
      vv[j] = b2f(kv[j * 2048 + 1024 + h * 64 + lane]);
    }
    float p[20];
#pragma unroll
    for (int j = 0; j < 5; ++j) p[j] = qv * kk[j];
    int idx = 5;
#pragma unroll
    for (int a = 0; a < 5; ++a)
#pragma unroll
      for (int c = a; c < 5; ++c) p[idx++] = vv[a] * vv[c];
#pragma unroll
    for (int t = 0; t < 20; ++t) {
      float v = p[t];
      v += __shfl_xor(v, 1, 64);  v += __shfl_xor(v, 2, 64);
      v += __shfl_xor(v, 4, 64);  v += __shfl_xor(v, 8, 64);
      v += __shfl_xor(v, 16, 64); v += __shfl_xor(v, 32, 64);
      p[t] = v;
    }
    if (lane == 0) {
#pragma unroll
      for (int t = 0; t < 20; ++t) red[wave][h][t] = p[t];
    }
  }
  __syncthreads();
  if (lane < 16) {
    int h = lane;
    float inv = 1.0f / (8.0f * fabsf(temp[0]));   // /sqrt(D) /|temperature|
    float out5[5];
#pragma unroll
    for (int s = 0; s < 5; ++s) {
      int r0 = routes[s * 3 + 0], r1 = routes[s * 3 + 1], r2 = routes[s * 3 + 2];
      float x0 = red[wave][h][r0] * inv;
      float x1 = red[wave][h][r1] * inv;
      float x2 = red[wave][h][r2] * inv;
      float mx = fmaxf(x0, fmaxf(x1, x2));
      float e0 = __expf(x0 - mx), e1 = __expf(x1 - mx), e2 = __expf(x2 - mx);
      float sden = e0 + e1 + e2;
      float a0 = e0 / sden, a1 = e1 / sden, a2 = e2 / sden;
      // Gram index: pairs (a<=b) at 5 + 5a - a(a-1)/2 + (b-a)
      const float* g = &red[wave][h][0];
      auto G = [&](int i, int j2) -> float {
        int a = i < j2 ? i : j2, bb = i < j2 ? j2 : i;
        return g[5 + 5 * a - ((a * (a - 1)) >> 1) + (bb - a)];
      };
      float val = a0 * a0 * G(r0, r0) + a1 * a1 * G(r1, r1) + a2 * a2 * G(r2, r2)
                + 2.f * (a0 * a1 * G(r0, r1) + a0 * a2 * G(r0, r2) + a1 * a2 * G(r1, r2));
      out5[s] = sqrtf(fmaxf(val, 0.f));
    }
#pragma unroll
    for (int s = 0; s < 5; ++s) {
      float v = out5[s];
      v += __shfl_xor(v, 1, 16); v += __shfl_xor(v, 2, 16);
      v += __shfl_xor(v, 4, 16); v += __shfl_xor(v, 8, 16);
      out5[s] = v * (1.f / 16.f);
    }
    if (lane == 0) {
#pragma unroll
      for (int s = 0; s < 5; ++s) si[(size_t)b * 5 + s] = out5[s];
    }
  }
}

// ---------------- gate: LN + gelu + Wg2 + combine + softmax -> aw ----------
__global__ __launch_bounds__(256) void gate_aw_kernel(
    const ushort* __restrict__ QH, const float* __restrict__ g_gamma,
    const float* __restrict__ g_beta, const float* __restrict__ Wg2,
    const float* __restrict__ bg2, const float* __restrict__ si,
    float* __restrict__ aw)
{
  int wave = threadIdx.x >> 6, lane = threadIdx.x & 63;
  int b = (blockIdx.x << 2) + wave;
  const ushort* hr = QH + (size_t)b * 1536 + 1024;
  float hv[8], s1 = 0.f, s2 = 0.f;
#pragma unroll
  for (int t = 0; t < 8; ++t) {
    float x = b2f(hr[t * 64 + lane]);
    hv[t] = x; s1 += x; s2 += x * x;
  }
#pragma unroll
  for (int m = 1; m < 64; m <<= 1) {
    s1 += __shfl_xor(s1, m, 64);
    s2 += __shfl_xor(s2, m, 64);
  }
  float mean = s1 * (1.f / 512.f);
  float var = s2 * (1.f / 512.f) - mean * mean;     // population var (ddof=0)
  float rstd = rsqrtf(var + 1e-5f);
  float acc5[5] = {0.f, 0.f, 0.f, 0.f, 0.f};
#pragma unroll
  for (int t = 0; t < 8; ++t) {
    int c = t * 64 + lane;
    float x = (hv[t] - mean) * rstd * g_gamma[c] + g_beta[c];
    float g = 0.5f * x * (1.f + erff(x * 0.70710678118654752f));  // exact gelu
#pragma unroll
    for (int s = 0; s < 5; ++s) acc5[s] += g * Wg2[s * 512 + c];
  }
#pragma unroll
  for (int s = 0; s < 5; ++s) {
    float v = acc5[s];
#pragma unroll
    for (int m = 1; m < 64; m <<= 1) v += __shfl_xor(v, m, 64);
    acc5[s] = v;
  }
  if (lane == 0) {
    float cs[5];
#pragma unroll
    for (int s = 0; s < 5; ++s)
      cs[s] = 0.7f * si[(size_t)b * 5 + s] + 0.3f * (acc5[s] + bg2[s]);
    float mx = cs[0];
#pragma unroll
    for (int s = 1; s < 5; ++s) mx = fmaxf(mx, cs[s]);
    float e[5], sum = 0.f;
#pragma unroll
    for (int s = 0; s < 5; ++s) { e[s] = __expf(cs[s] - mx); sum += e[s]; }
    float rs = 1.f / sum;
#pragma unroll
    for (int s = 0; s < 5; ++s) aw[(size_t)b * 5 + s] = e[s] * rs;
  }
}

// ---------------- final: combined_logits = sum_s aw_s * logits_s -----------
__global__ __launch_bounds__(256) void combine_kernel(
    const float* __restrict__ aw,
    const float* __restrict__ l0, const float* __restrict__ l1,
    const float* __restrict__ l2, const float* __restrict__ l3,
    const float* __restrict__ l4, float* __restrict__ out)
{
  int b = blockIdx.x, t = threadIdx.x;
  float a0 = aw[(size_t)b * 5 + 0], a1 = aw[(size_t)b * 5 + 1],
        a2 = aw[(size_t)b * 5 + 2], a3 = aw[(size_t)b * 5 + 3],
        a4 = aw[(size_t)b * 5 + 4];
  if (t < 250) {   // 1000 floats = 250 float4 per row
    size_t base = (size_t)b * 250 + t;
    float4 x0 = ((const float4*)l0)[base];
    float4 x1 = ((const float4*)l1)[base];
    float4 x2 = ((const float4*)l2)[base];
    float4 x3 = ((const float4*)l3)[base];
    float4 x4 = ((const float4*)l4)[base];
    float4 r;
    r.x = a0 * x0.x + a1 * x1.x + a2 * x2.x + a3 * x3.x + a4 * x4.x;
    r.y = a0 * x0.y + a1 * x1.y + a2 * x2.y + a3 * x3.y + a4 * x4.y;
    r.z = a0 * x0.z + a1 * x1.z + a2 * x2.z + a3 * x3.z + a4 * x4.z;
    r.w = a0 * x0.w + a1 * x1.w + a2 * x2.w + a3 * x3.w + a4 * x4.w;
    ((float4*)out)[base] = r;
  }
}

// ---------------------------------------------------------------------------
extern "C" void kernel_launch(void* const* d_in, const int* in_sizes, int n_in,
                              void* d_out, int out_size, void* d_ws, size_t ws_size,
                              hipStream_t stream) {
  const float* features = (const float*)d_in[0];
  const float* sf0 = (const float*)d_in[1];
  const float* sf1 = (const float*)d_in[2];
  const float* sf2 = (const float*)d_in[3];
  const float* sf3 = (const float*)d_in[4];
  const float* sf4 = (const float*)d_in[5];
  const float* lg0 = (const float*)d_in[6];
  const float* lg1 = (const float*)d_in[7];
  const float* lg2 = (const float*)d_in[8];
  const float* lg3 = (const float*)d_in[9];
  const float* lg4 = (const float*)d_in[10];
  const float* Ws0 = (const float*)d_in[11];
  const float* Ws1 = (const float*)d_in[12];
  const float* Ws2 = (const float*)d_in[13];
  const float* Ws3 = (const float*)d_in[14];
  const float* Ws4 = (const float*)d_in[15];
  const float* bs   = (const float*)d_in[16];
  const float* semb = (const float*)d_in[17];
  const float* Wq  = (const float*)d_in[18];
  const float* bq  = (const float*)d_in[19];
  const float* Wk  = (const float*)d_in[20];
  const float* bk  = (const float*)d_in[21];
  const float* Wv  = (const float*)d_in[22];
  const float* bv  = (const float*)d_in[23];
  const float* Wg1 = (const float*)d_in[24];
  const float* bg1 = (const float*)d_in[25];
  const float* g_gamma = (const float*)d_in[26];
  const float* g_beta  = (const float*)d_in[27];
  const float* Wg2 = (const float*)d_in[28];
  const float* bg2 = (const float*)d_in[29];
  const float* temp = (const float*)d_in[30];
  const int* routes = (const int*)d_in[31];

  // workspace layout (all 256B-aligned sizes)
  char* w = (char*)d_ws;
  ushort* sfc   = (ushort*)w;                 w += 8192ull * 1984 * 2;   // 32.5 MB
  ushort* featb = (ushort*)w;                 w += 8192ull * 1024 * 2;   // 16.8 MB
  ushort* Wqh   = (ushort*)w;                 w += 1536ull * 1024 * 2;   // [Wq;Wg1]
  ushort* WsT   = (ushort*)w;                 w += 1984ull * 1024 * 2;
  ushort* Akv   = (ushort*)w;                 w += 2048ull * 1984 * 2;   // [Wk;Wv]@Ws
  ushort* Wkvb  = (ushort*)w;                 w += 2048ull * 1024 * 2;
  ushort* bse   = (ushort*)w;                 w += 5ull * 1024 * 2 + 256 - (5ull*1024*2)%256;
  float*  bkv   = (float*)w;                  w += 2048ull * 4;
  float*  bqg1  = (float*)w;                  w += 1536ull * 4;
  float*  ckv   = (float*)w;                  w += 5ull * 2048 * 4;
  float*  si    = (float*)w;                  w += 8192ull * 5 * 4;
  ushort* QH    = (ushort*)w;                 w += 8192ull * 1536 * 2;   // [Q|h]
  ushort* KV    = (ushort*)w;                 w += 8192ull * 10240 * 2;  // 167.8 MB

  float* out = (float*)d_out;
  float* aw = out + 8192ull * 1000;           // output 1 region

  static const int offj[5] = {0, 64, 192, 448, 960};
  static const int scj[5]  = {64, 128, 256, 512, 1024};

  prep_rows<<<8192, 256, 0, stream>>>(features, sf0, sf1, sf2, sf3, sf4, featb, sfc);
  prep_w<<<3593, 256, 0, stream>>>(Wq, Wg1, Wk, Wv, bs, semb, bk, bv, bq, bg1,
                                   Wqh, Wkvb, bse, bkv, bqg1);
  transpose_ws<<<dim3(31, 16), 256, 0, stream>>>(Ws0, Ws1, Ws2, Ws3, Ws4, WsT);

  // Akv = [Wk;Wv] @ Ws_cat   (M=2048, N=1984, K=1024) -> bf16
  gemm_xwt<1><<<dim3(16, 16), 256, 0, stream>>>(Wkvb, 1024, WsT, 1024,
                                                (void*)Akv, 1984, nullptr,
                                                2048, 1984, 1024);
  // ckv = (bs+scale_emb) @ [Wk;Wv]^T + [bk;bv]  (M=5, N=2048, K=1024) -> f32
  gemm_xwt<0><<<dim3(1, 16), 256, 0, stream>>>(bse, 1024, Wkvb, 1024,
                                               (void*)ckv, 2048, bkv,
                                               5, 2048, 1024);
  // QH = features @ [Wq;Wg1]^T + [bq;bg1]  (M=8192, N=1536, K=1024) -> bf16
  gemm_xwt<1><<<dim3(64, 12), 256, 0, stream>>>(featb, 1024, Wqh, 1024,
                                                (void*)QH, 1536, bqg1,
                                                8192, 1536, 1024);
  // KV_j = sf_j @ Akv_j^T + ckv_j  (M=8192, N=2048, K=sc_j) -> bf16
  for (int j = 0; j < 5; ++j) {
    gemm_xwt<1><<<dim3(64, 16), 256, 0, stream>>>(
        sfc + offj[j], 1984, Akv + offj[j], 1984,
        (void*)(KV + j * 2048), 10240, ckv + (size_t)j * 2048,
        8192, 2048, scj[j]);
  }

  attn_si_kernel<<<2048, 256, 0, stream>>>(QH, KV, routes, temp, si);
  gate_aw_kernel<<<2048, 256, 0, stream>>>(QH, g_gamma, g_beta, Wg2, bg2, si, aw);
  combine_kernel<<<8192, 256, 0, stream>>>(aw, lg0, lg1, lg2, lg3, lg4, out);

  (void)in_sizes; (void)n_in; (void)out_size; (void)ws_size;
}

// Round 3
// 613.098 us; speedup vs baseline: 1.2342x; 1.2342x over previous
//
#include <hip/hip_runtime.h>

// ---------------------------------------------------------------------------
// B=8192, FD=1024, H=16, D=64, SCALES={64,128,256,512,1024}(sum1984), S=5,
// LW=3, C=1000, GD=512.
// Restructuring:
//   K_j = sf_j @ (Wk@Ws_j)^T + ck_j   (fold scale proj into K/V weights)
//   V_j = sf_j @ (Wv@Ws_j)^T + cv_j
//   scale_importance via Gram trick: ||sum_w a_w V_w||^2 = a^T G a
// R3: fix head-mean butterfly scale (xor{4,8,16,32} spans the 16 heads ->
//     divide by 16, not 64). Everything else identical to R2.
// ---------------------------------------------------------------------------

typedef short s16x8 __attribute__((ext_vector_type(8)));
typedef ushort u16x8 __attribute__((ext_vector_type(8)));
typedef float f32x4 __attribute__((ext_vector_type(4)));

__device__ __forceinline__ ushort f2b(float x) {
  unsigned u = __float_as_uint(x);
  return (ushort)((u + 0x7fffu + ((u >> 16) & 1u)) >> 16);  // RNE
}
__device__ __forceinline__ float b2f(ushort u) {
  return __uint_as_float(((unsigned)u) << 16);
}

// ---------------- GEMM: C[M,N] = X[M,K] @ W[N,K]^T (+ bias[N]) --------------
// bf16 inputs (as ushort), 128x128 tile, BK=64, 4 waves each 64x64 (4x4 MFMA).
// LDS chunk xor-swizzle: chunk(16B) at slot s of row r holds global chunk
// s^(r&7) -> fragment ds_read_b128 is <=2-way bank aliased (free, m136).
// Staging via global_load_lds: LDS dest is wave-uniform base + lane*16, the
// swizzle permutation is applied to the per-lane GLOBAL address.
template <int OUT_BF16>
__global__ __launch_bounds__(256, 2) void gemm_xwt(
    const ushort* __restrict__ X, int ldx, const ushort* __restrict__ W, int ldw,
    void* __restrict__ Cv, int ldo, const float* __restrict__ bias,
    int M, int N, int K)
{
  __shared__ __align__(16) ushort As[128 * 64];
  __shared__ __align__(16) ushort Bs[128 * 64];
  const int tid = threadIdx.x;
  const int bm = blockIdx.x << 7, bn = blockIdx.y << 7;
  const int wave = tid >> 6, lane = tid & 63;
  const int wm = (wave >> 1) << 6, wn = (wave & 1) << 6;
  const int quad = lane >> 4, l16 = lane & 15;

  f32x4 acc[4][4];
  const f32x4 zero = {0.f, 0.f, 0.f, 0.f};
#pragma unroll
  for (int i = 0; i < 4; ++i)
#pragma unroll
    for (int j = 0; j < 4; ++j) acc[i][j] = zero;

  const int ktiles = K >> 6;
  for (int kt = 0; kt < ktiles; ++kt) {
    const int kbase = kt << 6;
    __syncthreads();
#pragma unroll
    for (int i = 0; i < 4; ++i) {
      int wb = (i << 8) + (wave << 6);      // wave-uniform chunk base
      int flat = wb + lane;                 // this lane's dest chunk
      int row = flat >> 3, slot = flat & 7;
      int c = slot ^ (row & 7);
      int gr = bm + row; gr = (gr < M) ? gr : (M - 1);
      const ushort* src = X + (size_t)gr * ldx + kbase + (c << 3);
      __builtin_amdgcn_global_load_lds(
          (const __attribute__((address_space(1))) void*)src,
          (__attribute__((address_space(3))) void*)(As + ((size_t)wb << 3)),
          16, 0, 0);
    }
#pragma unroll
    for (int i = 0; i < 4; ++i) {
      int wb = (i << 8) + (wave << 6);
      int flat = wb + lane;
      int row = flat >> 3, slot = flat & 7;
      int c = slot ^ (row & 7);
      int gr = bn + row; gr = (gr < N) ? gr : (N - 1);
      const ushort* src = W + (size_t)gr * ldw + kbase + (c << 3);
      __builtin_amdgcn_global_load_lds(
          (const __attribute__((address_space(1))) void*)src,
          (__attribute__((address_space(3))) void*)(Bs + ((size_t)wb << 3)),
          16, 0, 0);
    }
    __syncthreads();
#pragma unroll
    for (int k0 = 0; k0 < 2; ++k0) {
      s16x8 af[4], bfr[4];
#pragma unroll
      for (int t = 0; t < 4; ++t) {
        int row = wm + (t << 4) + l16;
        int slot = ((k0 << 2) + quad) ^ (row & 7);
        af[t] = *(const s16x8*)(As + ((row << 3) + slot) * 8);
      }
#pragma unroll
      for (int t = 0; t < 4; ++t) {
        int row = wn + (t << 4) + l16;
        int slot = ((k0 << 2) + quad) ^ (row & 7);
        bfr[t] = *(const s16x8*)(Bs + ((row << 3) + slot) * 8);
      }
#pragma unroll
      for (int i = 0; i < 4; ++i)
#pragma unroll
        for (int j = 0; j < 4; ++j)
          acc[i][j] = __builtin_amdgcn_mfma_f32_16x16x32_bf16(af[i], bfr[j], acc[i][j], 0, 0, 0);
    }
  }

  // C/D layout: col = lane&15, row = quad*4 + reg   [measured m89/m91]
#pragma unroll
  for (int j = 0; j < 4; ++j) {
    int gn = bn + wn + (j << 4) + l16;
    if (gn < N) {
      float bv = bias ? bias[gn] : 0.f;
#pragma unroll
      for (int i = 0; i < 4; ++i) {
#pragma unroll
        for (int r = 0; r < 4; ++r) {
          int gm = bm + wm + (i << 4) + (quad << 2) + r;
          if (gm < M) {
            float val = acc[i][j][r] + bv;
            if (OUT_BF16) ((ushort*)Cv)[(size_t)gm * ldo + gn] = f2b(val);
            else          ((float*)Cv)[(size_t)gm * ldo + gn] = val;
          }
        }
      }
    }
  }
}

// ---------------- prep: per-row f32->bf16 of features + concat sf ----------
__global__ __launch_bounds__(256) void prep_rows(
    const float* __restrict__ feat,
    const float* __restrict__ s0, const float* __restrict__ s1,
    const float* __restrict__ s2, const float* __restrict__ s3,
    const float* __restrict__ s4,
    ushort* __restrict__ featb, ushort* __restrict__ sfc)
{
  int b = blockIdx.x, t = threadIdx.x;
  {
    float4 v = ((const float4*)(feat + (size_t)b * 1024))[t];
    ushort4 o; o.x = f2b(v.x); o.y = f2b(v.y); o.z = f2b(v.z); o.w = f2b(v.w);
    ((ushort4*)(featb + (size_t)b * 1024))[t] = o;
  }
  for (int c = t; c < 496; c += 256) {   // 496 float4 chunks per 1984-row
    int e = c << 2;
    const float* src;
    if (e < 64)        src = s0 + (size_t)b * 64 + e;
    else if (e < 192)  src = s1 + (size_t)b * 128 + (e - 64);
    else if (e < 448)  src = s2 + (size_t)b * 256 + (e - 192);
    else if (e < 960)  src = s3 + (size_t)b * 512 + (e - 448);
    else               src = s4 + (size_t)b * 1024 + (e - 960);
    float4 v = *(const float4*)src;
    ushort4 o; o.x = f2b(v.x); o.y = f2b(v.y); o.z = f2b(v.z); o.w = f2b(v.w);
    ((ushort4*)(sfc + (size_t)b * 1984))[c] = o;
  }
}

__device__ __forceinline__ void cvt4(const float* __restrict__ s, int si_,
                                     ushort* __restrict__ d, int di) {
  float4 v = ((const float4*)s)[si_];
  ushort4 o; o.x = f2b(v.x); o.y = f2b(v.y); o.z = f2b(v.z); o.w = f2b(v.w);
  ((ushort4*)d)[di] = o;
}

// ---------------- prep: weights to bf16, bias concats ----------------------
__global__ __launch_bounds__(256) void prep_w(
    const float* __restrict__ Wq, const float* __restrict__ Wg1,
    const float* __restrict__ Wk, const float* __restrict__ Wv,
    const float* __restrict__ bs, const float* __restrict__ semb,
    const float* __restrict__ bk, const float* __restrict__ bv,
    const float* __restrict__ bq, const float* __restrict__ bg1,
    ushort* __restrict__ Wqh, ushort* __restrict__ Wkvb,
    ushort* __restrict__ bse, float* __restrict__ bkv, float* __restrict__ bqg1)
{
  int id = blockIdx.x * 256 + threadIdx.x;   // float4-chunk id
  if (id < 262144) { cvt4(Wq, id, Wqh, id); return; }
  id -= 262144;
  if (id < 131072) { cvt4(Wg1, id, Wqh + 1048576, id); return; }
  id -= 131072;
  if (id < 262144) { cvt4(Wk, id, Wkvb, id); return; }
  id -= 262144;
  if (id < 262144) { cvt4(Wv, id, Wkvb + 1048576, id); return; }
  id -= 262144;
  if (id < 1280) {   // bse = (bs + scale_emb) -> bf16, [5][1024]
    float4 a = ((const float4*)bs)[id];
    float4 b = ((const float4*)semb)[id];
    ushort4 o; o.x = f2b(a.x + b.x); o.y = f2b(a.y + b.y);
    o.z = f2b(a.z + b.z); o.w = f2b(a.w + b.w);
    ((ushort4*)bse)[id] = o;
    return;
  }
  id -= 1280;
  if (id < 512) {    // bkv = concat(bk, bv) f32 [2048]
    float4 v = (id < 256) ? ((const float4*)bk)[id] : ((const float4*)bv)[id - 256];
    ((float4*)bkv)[id] = v;
    return;
  }
  id -= 512;
  if (id < 384) {    // bqg1 = concat(bq, bg1) f32 [1536]
    float4 v = (id < 256) ? ((const float4*)bq)[id] : ((const float4*)bg1)[id - 256];
    ((float4*)bqg1)[id] = v;
  }
}

// ---------------- prep: WsT[off_j+k][c] = Ws_j[c][k]  (f32 -> bf16) --------
__global__ __launch_bounds__(256) void transpose_ws(
    const float* __restrict__ Ws0, const float* __restrict__ Ws1,
    const float* __restrict__ Ws2, const float* __restrict__ Ws3,
    const float* __restrict__ Ws4, ushort* __restrict__ WsT)
{
  __shared__ float tile[64][65];
  int kt = blockIdx.x, ct = blockIdx.y;
  const float* Ws; int kb, scj, offj;
  if (kt < 1)       { Ws = Ws0; kb = kt;      scj = 64;   offj = 0;   }
  else if (kt < 3)  { Ws = Ws1; kb = kt - 1;  scj = 128;  offj = 64;  }
  else if (kt < 7)  { Ws = Ws2; kb = kt - 3;  scj = 256;  offj = 192; }
  else if (kt < 15) { Ws = Ws3; kb = kt - 7;  scj = 512;  offj = 448; }
  else              { Ws = Ws4; kb = kt - 15; scj = 1024; offj = 960; }
  int c0 = ct << 6, k0 = kb << 6;
  int col = threadIdx.x & 63, r4 = threadIdx.x >> 6;
#pragma unroll
  for (int p = 0; p < 16; ++p) {
    int r = (p << 2) + r4;
    tile[r][col] = Ws[(size_t)(c0 + r) * scj + k0 + col];
  }
  __syncthreads();
#pragma unroll
  for (int p = 0; p < 16; ++p) {
    int r = (p << 2) + r4;
    WsT[(size_t)(offj + k0 + r) * 1024 + c0 + col] = f2b(tile[col][r]);
  }
}

// ---------------- fused attn-reduction + gate + softmax -> aw --------------
// One wave per row b. Lane l covers head h=l>>2, elements [16l,16l+16) of the
// 1024-elem (h,d) space. 20 dot partials in registers; reduce within the
// 4-lane head group (2 butterfly steps). Per-head softmax over routed scales,
// Gram quadratic form, head-mean via butterfly over lane bits 2..5 (the head
// index) -> sums the 16 per-head values once each -> divide by 16.
// Then gate: LN(512) + exact gelu + Wg2 + combine + softmax.
__global__ __launch_bounds__(256) void attn_gate_kernel(
    const ushort* __restrict__ QH, const ushort* __restrict__ KV,
    const int* __restrict__ routes, const float* __restrict__ temp,
    const float* __restrict__ g_gamma, const float* __restrict__ g_beta,
    const float* __restrict__ Wg2, const float* __restrict__ bg2,
    float* __restrict__ aw)
{
  const int wave = threadIdx.x >> 6, lane = threadIdx.x & 63;
  const int b = (blockIdx.x << 2) + wave;
  const ushort* q = QH + (size_t)b * 1536 + (lane << 4);
  const ushort* kv = KV + (size_t)b * 10240 + (lane << 4);

  float qv[16];
  {
    u16x8 q0 = ((const u16x8*)q)[0];
    u16x8 q1 = ((const u16x8*)q)[1];
#pragma unroll
    for (int t = 0; t < 8; ++t) { qv[t] = b2f(q0[t]); qv[8 + t] = b2f(q1[t]); }
  }
  float vv[5][16];
  float p[20];
#pragma unroll
  for (int j = 0; j < 5; ++j) {
    u16x8 k0 = ((const u16x8*)(kv + j * 2048))[0];
    u16x8 k1 = ((const u16x8*)(kv + j * 2048))[1];
    u16x8 v0 = ((const u16x8*)(kv + j * 2048 + 1024))[0];
    u16x8 v1 = ((const u16x8*)(kv + j * 2048 + 1024))[1];
    float s = 0.f;
#pragma unroll
    for (int t = 0; t < 8; ++t) {
      s += qv[t] * b2f(k0[t]) + qv[8 + t] * b2f(k1[t]);
      vv[j][t] = b2f(v0[t]); vv[j][8 + t] = b2f(v1[t]);
    }
    p[j] = s;
  }
  {
    int idx = 5;
#pragma unroll
    for (int a = 0; a < 5; ++a)
#pragma unroll
      for (int c2 = a; c2 < 5; ++c2) {
        float s = 0.f;
#pragma unroll
        for (int t = 0; t < 16; ++t) s += vv[a][t] * vv[c2][t];
        p[idx++] = s;
      }
  }
  // reduce the 20 sums within each 4-lane head group
#pragma unroll
  for (int t = 0; t < 20; ++t) {
    p[t] += __shfl_xor(p[t], 1, 64);
    p[t] += __shfl_xor(p[t], 2, 64);
  }
  // per-head routed softmax + Gram quadratic form (all 4 lanes redundantly)
  float inv = 1.0f / (8.0f * fabsf(temp[0]));   // /sqrt(D) /|temperature|
  float si5[5];
#pragma unroll
  for (int s = 0; s < 5; ++s) {
    int r0 = routes[s * 3 + 0], r1 = routes[s * 3 + 1], r2 = routes[s * 3 + 2];
    float x0 = p[r0] * inv, x1 = p[r1] * inv, x2 = p[r2] * inv;
    float mx = fmaxf(x0, fmaxf(x1, x2));
    float e0 = __expf(x0 - mx), e1 = __expf(x1 - mx), e2 = __expf(x2 - mx);
    float den = e0 + e1 + e2;
    float a0 = e0 / den, a1 = e1 / den, a2 = e2 / den;
    auto G = [&](int i, int j2) -> float {
      int a = i < j2 ? i : j2, bb = i < j2 ? j2 : i;
      return p[5 + 5 * a - ((a * (a - 1)) >> 1) + (bb - a)];
    };
    float val = a0 * a0 * G(r0, r0) + a1 * a1 * G(r1, r1) + a2 * a2 * G(r2, r2)
              + 2.f * (a0 * a1 * G(r0, r1) + a0 * a2 * G(r0, r2) + a1 * a2 * G(r1, r2));
    float o = sqrtf(fmaxf(val, 0.f));
    // head-mean: butterfly over lane bits 2..5 sums one value per head
    o += __shfl_xor(o, 4, 64);  o += __shfl_xor(o, 8, 64);
    o += __shfl_xor(o, 16, 64); o += __shfl_xor(o, 32, 64);
    si5[s] = o * (1.f / 16.f);
  }

  // ---- gate branch: h = QH[b][1024..1536) (512 elems, 8/lane contiguous)
  const ushort* hr = QH + (size_t)b * 1536 + 1024 + (lane << 3);
  float hv[8], s1 = 0.f, s2 = 0.f;
  {
    u16x8 h8 = *(const u16x8*)hr;
#pragma unroll
    for (int t = 0; t < 8; ++t) {
      float x = b2f(h8[t]);
      hv[t] = x; s1 += x; s2 += x * x;
    }
  }
#pragma unroll
  for (int m = 1; m < 64; m <<= 1) {
    s1 += __shfl_xor(s1, m, 64);
    s2 += __shfl_xor(s2, m, 64);
  }
  float mean = s1 * (1.f / 512.f);
  float var = s2 * (1.f / 512.f) - mean * mean;     // population var (ddof=0)
  float rstd = rsqrtf(var + 1e-5f);
  float4 gg0 = ((const float4*)(g_gamma + (lane << 3)))[0];
  float4 gg1 = ((const float4*)(g_gamma + (lane << 3)))[1];
  float4 gb0 = ((const float4*)(g_beta + (lane << 3)))[0];
  float4 gb1 = ((const float4*)(g_beta + (lane << 3)))[1];
  float gam[8] = {gg0.x, gg0.y, gg0.z, gg0.w, gg1.x, gg1.y, gg1.z, gg1.w};
  float bet[8] = {gb0.x, gb0.y, gb0.z, gb0.w, gb1.x, gb1.y, gb1.z, gb1.w};
  float gel[8];
#pragma unroll
  for (int t = 0; t < 8; ++t) {
    float x = (hv[t] - mean) * rstd * gam[t] + bet[t];
    gel[t] = 0.5f * x * (1.f + erff(x * 0.70710678118654752f));  // exact gelu
  }
  float acc5[5];
#pragma unroll
  for (int s = 0; s < 5; ++s) {
    const float* wr = Wg2 + s * 512 + (lane << 3);
    float4 w0 = ((const float4*)wr)[0];
    float4 w1 = ((const float4*)wr)[1];
    float a = gel[0] * w0.x + gel[1] * w0.y + gel[2] * w0.z + gel[3] * w0.w
            + gel[4] * w1.x + gel[5] * w1.y + gel[6] * w1.z + gel[7] * w1.w;
#pragma unroll
    for (int m = 1; m < 64; m <<= 1) a += __shfl_xor(a, m, 64);
    acc5[s] = a;
  }
  if (lane == 0) {
    float cs[5];
#pragma unroll
    for (int s = 0; s < 5; ++s)
      cs[s] = 0.7f * si5[s] + 0.3f * (acc5[s] + bg2[s]);
    float mx = cs[0];
#pragma unroll
    for (int s = 1; s < 5; ++s) mx = fmaxf(mx, cs[s]);
    float e[5], sum = 0.f;
#pragma unroll
    for (int s = 0; s < 5; ++s) { e[s] = __expf(cs[s] - mx); sum += e[s]; }
    float rs = 1.f / sum;
#pragma unroll
    for (int s = 0; s < 5; ++s) aw[(size_t)b * 5 + s] = e[s] * rs;
  }
}

// ---------------- final: combined_logits = sum_s aw_s * logits_s -----------
__global__ __launch_bounds__(256) void combine_kernel(
    const float* __restrict__ aw,
    const float* __restrict__ l0, const float* __restrict__ l1,
    const float* __restrict__ l2, const float* __restrict__ l3,
    const float* __restrict__ l4, float* __restrict__ out)
{
  int b = blockIdx.x, t = threadIdx.x;
  float a0 = aw[(size_t)b * 5 + 0], a1 = aw[(size_t)b * 5 + 1],
        a2 = aw[(size_t)b * 5 + 2], a3 = aw[(size_t)b * 5 + 3],
        a4 = aw[(size_t)b * 5 + 4];
  if (t < 250) {   // 1000 floats = 250 float4 per row
    size_t base = (size_t)b * 250 + t;
    float4 x0 = ((const float4*)l0)[base];
    float4 x1 = ((const float4*)l1)[base];
    float4 x2 = ((const float4*)l2)[base];
    float4 x3 = ((const float4*)l3)[base];
    float4 x4 = ((const float4*)l4)[base];
    float4 r;
    r.x = a0 * x0.x + a1 * x1.x + a2 * x2.x + a3 * x3.x + a4 * x4.x;
    r.y = a0 * x0.y + a1 * x1.y + a2 * x2.y + a3 * x3.y + a4 * x4.y;
    r.z = a0 * x0.z + a1 * x1.z + a2 * x2.z + a3 * x3.z + a4 * x4.z;
    r.w = a0 * x0.w + a1 * x1.w + a2 * x2.w + a3 * x3.w + a4 * x4.w;
    ((float4*)out)[base] = r;
  }
}

// ---------------------------------------------------------------------------
extern "C" void kernel_launch(void* const* d_in, const int* in_sizes, int n_in,
                              void* d_out, int out_size, void* d_ws, size_t ws_size,
                              hipStream_t stream) {
  const float* features = (const float*)d_in[0];
  const float* sf0 = (const float*)d_in[1];
  const float* sf1 = (const float*)d_in[2];
  const float* sf2 = (const float*)d_in[3];
  const float* sf3 = (const float*)d_in[4];
  const float* sf4 = (const float*)d_in[5];
  const float* lg0 = (const float*)d_in[6];
  const float* lg1 = (const float*)d_in[7];
  const float* lg2 = (const float*)d_in[8];
  const float* lg3 = (const float*)d_in[9];
  const float* lg4 = (const float*)d_in[10];
  const float* Ws0 = (const float*)d_in[11];
  const float* Ws1 = (const float*)d_in[12];
  const float* Ws2 = (const float*)d_in[13];
  const float* Ws3 = (const float*)d_in[14];
  const float* Ws4 = (const float*)d_in[15];
  const float* bs   = (const float*)d_in[16];
  const float* semb = (const float*)d_in[17];
  const float* Wq  = (const float*)d_in[18];
  const float* bq  = (const float*)d_in[19];
  const float* Wk  = (const float*)d_in[20];
  const float* bk  = (const float*)d_in[21];
  const float* Wv  = (const float*)d_in[22];
  const float* bv  = (const float*)d_in[23];
  const float* Wg1 = (const float*)d_in[24];
  const float* bg1 = (const float*)d_in[25];
  const float* g_gamma = (const float*)d_in[26];
  const float* g_beta  = (const float*)d_in[27];
  const float* Wg2 = (const float*)d_in[28];
  const float* bg2 = (const float*)d_in[29];
  const float* temp = (const float*)d_in[30];
  const int* routes = (const int*)d_in[31];

  // workspace layout
  char* w = (char*)d_ws;
  ushort* sfc   = (ushort*)w;                 w += 8192ull * 1984 * 2;   // 32.5 MB
  ushort* featb = (ushort*)w;                 w += 8192ull * 1024 * 2;   // 16.8 MB
  ushort* Wqh   = (ushort*)w;                 w += 1536ull * 1024 * 2;   // [Wq;Wg1]
  ushort* WsT   = (ushort*)w;                 w += 1984ull * 1024 * 2;
  ushort* Akv   = (ushort*)w;                 w += 2048ull * 1984 * 2;   // [Wk;Wv]@Ws
  ushort* Wkvb  = (ushort*)w;                 w += 2048ull * 1024 * 2;
  ushort* bse   = (ushort*)w;                 w += 5ull * 1024 * 2 + 256 - (5ull*1024*2)%256;
  float*  bkv   = (float*)w;                  w += 2048ull * 4;
  float*  bqg1  = (float*)w;                  w += 1536ull * 4;
  float*  ckv   = (float*)w;                  w += 5ull * 2048 * 4;
  float*  si_unused = (float*)w;              w += 8192ull * 5 * 4;
  ushort* QH    = (ushort*)w;                 w += 8192ull * 1536 * 2;   // [Q|h]
  ushort* KV    = (ushort*)w;                 w += 8192ull * 10240 * 2;  // 167.8 MB
  (void)si_unused;

  float* out = (float*)d_out;
  float* aw = out + 8192ull * 1000;           // output 1 region

  static const int offj[5] = {0, 64, 192, 448, 960};
  static const int scj[5]  = {64, 128, 256, 512, 1024};

  prep_rows<<<8192, 256, 0, stream>>>(features, sf0, sf1, sf2, sf3, sf4, featb, sfc);
  prep_w<<<3593, 256, 0, stream>>>(Wq, Wg1, Wk, Wv, bs, semb, bk, bv, bq, bg1,
                                   Wqh, Wkvb, bse, bkv, bqg1);
  transpose_ws<<<dim3(31, 16), 256, 0, stream>>>(Ws0, Ws1, Ws2, Ws3, Ws4, WsT);

  // Akv = [Wk;Wv] @ Ws_cat   (M=2048, N=1984, K=1024) -> bf16
  gemm_xwt<1><<<dim3(16, 16), 256, 0, stream>>>(Wkvb, 1024, WsT, 1024,
                                                (void*)Akv, 1984, nullptr,
                                                2048, 1984, 1024);
  // ckv = (bs+scale_emb) @ [Wk;Wv]^T + [bk;bv]  (M=5, N=2048, K=1024) -> f32
  gemm_xwt<0><<<dim3(1, 16), 256, 0, stream>>>(bse, 1024, Wkvb, 1024,
                                               (void*)ckv, 2048, bkv,
                                               5, 2048, 1024);
  // QH = features @ [Wq;Wg1]^T + [bq;bg1]  (M=8192, N=1536, K=1024) -> bf16
  gemm_xwt<1><<<dim3(64, 12), 256, 0, stream>>>(featb, 1024, Wqh, 1024,
                                                (void*)QH, 1536, bqg1,
                                                8192, 1536, 1024);
  // KV_j = sf_j @ Akv_j^T + ckv_j  (M=8192, N=2048, K=sc_j) -> bf16
  for (int j = 0; j < 5; ++j) {
    gemm_xwt<1><<<dim3(64, 16), 256, 0, stream>>>(
        sfc + offj[j], 1984, Akv + offj[j], 1984,
        (void*)(KV + j * 2048), 10240, ckv + (size_t)j * 2048,
        8192, 2048, scj[j]);
  }

  attn_gate_kernel<<<2048, 256, 0, stream>>>(QH, KV, routes, temp,
                                             g_gamma, g_beta, Wg2, bg2, aw);
  combine_kernel<<<8192, 256, 0, stream>>>(aw, lg0, lg1, lg2, lg3, lg4, out);

  (void)in_sizes; (void)n_in; (void)out_size; (void)ws_size;
}

// Round 4
// 479.894 us; speedup vs baseline: 1.5768x; 1.2776x over previous
//
#include <hip/hip_runtime.h>

// ---------------------------------------------------------------------------
// B=8192, FD=1024, H=16, D=64, SCALES={64,128,256,512,1024}(sum1984), S=5,
// LW=3, C=1000, GD=512.
// Restructuring:
//   K_j = sf_j @ (Wk@Ws_j)^T + ck_j   (fold scale proj into K/V weights)
//   V_j = sf_j @ (Wv@Ws_j)^T + cv_j
//   scale_importance via Gram trick: ||sum_w a_w V_w||^2 = a^T G a
// R4: (a) 5 KV GEMMs + QH GEMM fused into one dispatch (blockIdx.z job table),
//     (b) LDS-staged coalesced bf16 epilogue (kills 1.58x write amplification),
//     (c) ckv M=5 GEMM -> wave-per-output dot kernel, (d) prep kernels fused.
//     Launches 13 -> 6.
// ---------------------------------------------------------------------------

typedef short s16x8 __attribute__((ext_vector_type(8)));
typedef ushort u16x8 __attribute__((ext_vector_type(8)));
typedef float f32x4 __attribute__((ext_vector_type(4)));

__device__ __forceinline__ ushort f2b(float x) {
  unsigned u = __float_as_uint(x);
  return (ushort)((u + 0x7fffu + ((u >> 16) & 1u)) >> 16);  // RNE
}
__device__ __forceinline__ float b2f(ushort u) {
  return __uint_as_float(((unsigned)u) << 16);
}

// ---------------- mega GEMM: 6 jobs, C[8192,N] = X @ W^T + bias -------------
// All jobs: M=8192, N multiple of 128, K multiple of 64.
// 128x128 tile, BK=64, 4 waves each 64x64 (4x4 MFMA 16x16x32 bf16).
// LDS chunk xor-swizzle (16B chunk at slot s of row r holds global chunk
// s^(r&7)); staging via global_load_lds width=16 (wave-uniform LDS base,
// swizzle applied to the per-lane GLOBAL address).
// Epilogue: acc+bias -> bf16 via 32KB LDS C-tile (reuses As/Bs), then
// 16B/lane coalesced global stores (256B contiguous segments).
struct GemmJob {
  const ushort* X; const ushort* W; ushort* C; const float* bias;
  int ldx, ldw, ldo, K, N, pad;
};
struct GemmJobs { GemmJob j[6]; };

__global__ __launch_bounds__(256, 2) void mega_gemm(GemmJobs jobs)
{
  __shared__ __align__(16) ushort smem[2][128 * 64];   // As | Bs, 32 KB
  ushort* As = smem[0];
  ushort* Bs = smem[1];
  const GemmJob jb = jobs.j[blockIdx.z];
  const int bn = blockIdx.y << 7;
  if (bn >= jb.N) return;                      // QH plane has N=1536 (12 tiles)
  const int bm = blockIdx.x << 7;
  const int tid = threadIdx.x;
  const int wave = tid >> 6, lane = tid & 63;
  const int wm = (wave >> 1) << 6, wn = (wave & 1) << 6;
  const int quad = lane >> 4, l16 = lane & 15;

  f32x4 acc[4][4];
  const f32x4 zero = {0.f, 0.f, 0.f, 0.f};
#pragma unroll
  for (int i = 0; i < 4; ++i)
#pragma unroll
    for (int j = 0; j < 4; ++j) acc[i][j] = zero;

  const int ktiles = jb.K >> 6;
  for (int kt = 0; kt < ktiles; ++kt) {
    const int kbase = kt << 6;
    __syncthreads();
#pragma unroll
    for (int i = 0; i < 4; ++i) {
      int wb = (i << 8) + (wave << 6);      // wave-uniform chunk base
      int flat = wb + lane;                 // this lane's dest chunk
      int row = flat >> 3, slot = flat & 7;
      int c = slot ^ (row & 7);
      const ushort* src = jb.X + (size_t)(bm + row) * jb.ldx + kbase + (c << 3);
      __builtin_amdgcn_global_load_lds(
          (const __attribute__((address_space(1))) void*)src,
          (__attribute__((address_space(3))) void*)(As + ((size_t)wb << 3)),
          16, 0, 0);
    }
#pragma unroll
    for (int i = 0; i < 4; ++i) {
      int wb = (i << 8) + (wave << 6);
      int flat = wb + lane;
      int row = flat >> 3, slot = flat & 7;
      int c = slot ^ (row & 7);
      const ushort* src = jb.W + (size_t)(bn + row) * jb.ldw + kbase + (c << 3);
      __builtin_amdgcn_global_load_lds(
          (const __attribute__((address_space(1))) void*)src,
          (__attribute__((address_space(3))) void*)(Bs + ((size_t)wb << 3)),
          16, 0, 0);
    }
    __syncthreads();
#pragma unroll
    for (int k0 = 0; k0 < 2; ++k0) {
      s16x8 af[4], bfr[4];
#pragma unroll
      for (int t = 0; t < 4; ++t) {
        int row = wm + (t << 4) + l16;
        int slot = ((k0 << 2) + quad) ^ (row & 7);
        af[t] = *(const s16x8*)(As + ((row << 3) + slot) * 8);
      }
#pragma unroll
      for (int t = 0; t < 4; ++t) {
        int row = wn + (t << 4) + l16;
        int slot = ((k0 << 2) + quad) ^ (row & 7);
        bfr[t] = *(const s16x8*)(Bs + ((row << 3) + slot) * 8);
      }
#pragma unroll
      for (int i = 0; i < 4; ++i)
#pragma unroll
        for (int j = 0; j < 4; ++j)
          acc[i][j] = __builtin_amdgcn_mfma_f32_16x16x32_bf16(af[i], bfr[j], acc[i][j], 0, 0, 0);
    }
  }

  // epilogue: C/D layout col=lane&15, row=quad*4+reg  [m89/m91]
  __syncthreads();                       // all waves done reading As/Bs
  ushort* Cs = (ushort*)smem;            // 128*128 bf16 = 32 KB
#pragma unroll
  for (int j = 0; j < 4; ++j) {
    float bv = jb.bias[bn + wn + (j << 4) + l16];
#pragma unroll
    for (int i = 0; i < 4; ++i) {
      int row = wm + (i << 4) + (quad << 2);
      int col = wn + (j << 4) + l16;
#pragma unroll
      for (int r = 0; r < 4; ++r)
        Cs[(row + r) * 128 + col] = f2b(acc[i][j][r] + bv);
    }
  }
  __syncthreads();
#pragma unroll
  for (int p = 0; p < 8; ++p) {
    int chunk = (p << 8) + tid;          // 2048 chunks of 8 ushorts
    int row = chunk >> 4, c8 = chunk & 15;
    int4 v = *(const int4*)(Cs + row * 128 + (c8 << 3));
    *(int4*)(jb.C + (size_t)(bm + row) * jb.ldo + bn + (c8 << 3)) = v;
  }
}

// ---------------- GEMM (generic, clamped): used for Akv only ----------------
__global__ __launch_bounds__(256, 2) void gemm_xwt(
    const ushort* __restrict__ X, int ldx, const ushort* __restrict__ W, int ldw,
    ushort* __restrict__ Cv, int ldo, int M, int N, int K)
{
  __shared__ __align__(16) ushort As[128 * 64];
  __shared__ __align__(16) ushort Bs[128 * 64];
  const int tid = threadIdx.x;
  const int bm = blockIdx.x << 7, bn = blockIdx.y << 7;
  const int wave = tid >> 6, lane = tid & 63;
  const int wm = (wave >> 1) << 6, wn = (wave & 1) << 6;
  const int quad = lane >> 4, l16 = lane & 15;

  f32x4 acc[4][4];
  const f32x4 zero = {0.f, 0.f, 0.f, 0.f};
#pragma unroll
  for (int i = 0; i < 4; ++i)
#pragma unroll
    for (int j = 0; j < 4; ++j) acc[i][j] = zero;

  const int ktiles = K >> 6;
  for (int kt = 0; kt < ktiles; ++kt) {
    const int kbase = kt << 6;
    __syncthreads();
#pragma unroll
    for (int i = 0; i < 4; ++i) {
      int wb = (i << 8) + (wave << 6);
      int flat = wb + lane;
      int row = flat >> 3, slot = flat & 7;
      int c = slot ^ (row & 7);
      int gr = bm + row; gr = (gr < M) ? gr : (M - 1);
      const ushort* src = X + (size_t)gr * ldx + kbase + (c << 3);
      __builtin_amdgcn_global_load_lds(
          (const __attribute__((address_space(1))) void*)src,
          (__attribute__((address_space(3))) void*)(As + ((size_t)wb << 3)),
          16, 0, 0);
    }
#pragma unroll
    for (int i = 0; i < 4; ++i) {
      int wb = (i << 8) + (wave << 6);
      int flat = wb + lane;
      int row = flat >> 3, slot = flat & 7;
      int c = slot ^ (row & 7);
      int gr = bn + row; gr = (gr < N) ? gr : (N - 1);
      const ushort* src = W + (size_t)gr * ldw + kbase + (c << 3);
      __builtin_amdgcn_global_load_lds(
          (const __attribute__((address_space(1))) void*)src,
          (__attribute__((address_space(3))) void*)(Bs + ((size_t)wb << 3)),
          16, 0, 0);
    }
    __syncthreads();
#pragma unroll
    for (int k0 = 0; k0 < 2; ++k0) {
      s16x8 af[4], bfr[4];
#pragma unroll
      for (int t = 0; t < 4; ++t) {
        int row = wm + (t << 4) + l16;
        int slot = ((k0 << 2) + quad) ^ (row & 7);
        af[t] = *(const s16x8*)(As + ((row << 3) + slot) * 8);
      }
#pragma unroll
      for (int t = 0; t < 4; ++t) {
        int row = wn + (t << 4) + l16;
        int slot = ((k0 << 2) + quad) ^ (row & 7);
        bfr[t] = *(const s16x8*)(Bs + ((row << 3) + slot) * 8);
      }
#pragma unroll
      for (int i = 0; i < 4; ++i)
#pragma unroll
        for (int j = 0; j < 4; ++j)
          acc[i][j] = __builtin_amdgcn_mfma_f32_16x16x32_bf16(af[i], bfr[j], acc[i][j], 0, 0, 0);
    }
  }
#pragma unroll
  for (int j = 0; j < 4; ++j) {
    int gn = bn + wn + (j << 4) + l16;
    if (gn < N) {
#pragma unroll
      for (int i = 0; i < 4; ++i) {
#pragma unroll
        for (int r = 0; r < 4; ++r) {
          int gm = bm + wm + (i << 4) + (quad << 2) + r;
          if (gm < M) ((ushort*)Cv)[(size_t)gm * ldo + gn] = f2b(acc[i][j][r]);
        }
      }
    }
  }
}

// ---------------- ckv: wave-per-output dot ---------------------------------
// ckv[s][n] = bkv[n] + sum_k bse[s][k]*Wkvb[n][k]   (5 x 2048 outputs)
__global__ __launch_bounds__(256) void ckv_kernel(
    const ushort* __restrict__ bse, const ushort* __restrict__ Wkvb,
    const float* __restrict__ bkv, float* __restrict__ ckv)
{
  int w = (blockIdx.x << 2) + (threadIdx.x >> 6);
  int lane = threadIdx.x & 63;
  int s = w >> 11, n = w & 2047;
  const ushort* a = bse + s * 1024 + (lane << 4);
  const ushort* b = Wkvb + (size_t)n * 1024 + (lane << 4);
  u16x8 a0 = ((const u16x8*)a)[0], a1 = ((const u16x8*)a)[1];
  u16x8 b0 = ((const u16x8*)b)[0], b1 = ((const u16x8*)b)[1];
  float sum = 0.f;
#pragma unroll
  for (int t = 0; t < 8; ++t)
    sum += b2f(a0[t]) * b2f(b0[t]) + b2f(a1[t]) * b2f(b1[t]);
#pragma unroll
  for (int m = 1; m < 64; m <<= 1) sum += __shfl_xor(sum, m, 64);
  if (lane == 0) ckv[s * 2048 + n] = sum + bkv[n];
}

// ---------------- fused prep: rows + weights + Ws transpose ----------------
__device__ __forceinline__ void cvt4(const float* __restrict__ s, int si_,
                                     ushort* __restrict__ d, int di) {
  float4 v = ((const float4*)s)[si_];
  ushort4 o; o.x = f2b(v.x); o.y = f2b(v.y); o.z = f2b(v.z); o.w = f2b(v.w);
  ((ushort4*)d)[di] = o;
}

__global__ __launch_bounds__(256) void prep_all(
    const float* __restrict__ feat,
    const float* __restrict__ s0, const float* __restrict__ s1,
    const float* __restrict__ s2, const float* __restrict__ s3,
    const float* __restrict__ s4,
    const float* __restrict__ Wq, const float* __restrict__ Wg1,
    const float* __restrict__ Wk, const float* __restrict__ Wv,
    const float* __restrict__ bs, const float* __restrict__ semb,
    const float* __restrict__ bk, const float* __restrict__ bv,
    const float* __restrict__ bq, const float* __restrict__ bg1,
    const float* __restrict__ Ws0, const float* __restrict__ Ws1,
    const float* __restrict__ Ws2, const float* __restrict__ Ws3,
    const float* __restrict__ Ws4,
    ushort* __restrict__ featb, ushort* __restrict__ sfc,
    ushort* __restrict__ Wqh, ushort* __restrict__ Wkvb,
    ushort* __restrict__ bse, float* __restrict__ bkv,
    float* __restrict__ bqg1, ushort* __restrict__ WsT)
{
  __shared__ float tile[64][65];
  int bx = blockIdx.x, t = threadIdx.x;
  if (bx < 8192) {                        // --- per-row cvt + concat ---
    int b = bx;
    {
      float4 v = ((const float4*)(feat + (size_t)b * 1024))[t];
      ushort4 o; o.x = f2b(v.x); o.y = f2b(v.y); o.z = f2b(v.z); o.w = f2b(v.w);
      ((ushort4*)(featb + (size_t)b * 1024))[t] = o;
    }
    for (int c = t; c < 496; c += 256) {
      int e = c << 2;
      const float* src;
      if (e < 64)        src = s0 + (size_t)b * 64 + e;
      else if (e < 192)  src = s1 + (size_t)b * 128 + (e - 64);
      else if (e < 448)  src = s2 + (size_t)b * 256 + (e - 192);
      else if (e < 960)  src = s3 + (size_t)b * 512 + (e - 448);
      else               src = s4 + (size_t)b * 1024 + (e - 960);
      float4 v = *(const float4*)src;
      ushort4 o; o.x = f2b(v.x); o.y = f2b(v.y); o.z = f2b(v.z); o.w = f2b(v.w);
      ((ushort4*)(sfc + (size_t)b * 1984))[c] = o;
    }
    return;
  }
  if (bx < 11785) {                       // --- weight cvt + bias concat ---
    int id = (bx - 8192) * 256 + t;
    if (id < 262144) { cvt4(Wq, id, Wqh, id); return; }
    id -= 262144;
    if (id < 131072) { cvt4(Wg1, id, Wqh + 1048576, id); return; }
    id -= 131072;
    if (id < 262144) { cvt4(Wk, id, Wkvb, id); return; }
    id -= 262144;
    if (id < 262144) { cvt4(Wv, id, Wkvb + 1048576, id); return; }
    id -= 262144;
    if (id < 1280) {
      float4 a = ((const float4*)bs)[id];
      float4 b = ((const float4*)semb)[id];
      ushort4 o; o.x = f2b(a.x + b.x); o.y = f2b(a.y + b.y);
      o.z = f2b(a.z + b.z); o.w = f2b(a.w + b.w);
      ((ushort4*)bse)[id] = o;
      return;
    }
    id -= 1280;
    if (id < 512) {
      float4 v = (id < 256) ? ((const float4*)bk)[id] : ((const float4*)bv)[id - 256];
      ((float4*)bkv)[id] = v;
      return;
    }
    id -= 512;
    if (id < 384) {
      float4 v = (id < 256) ? ((const float4*)bq)[id] : ((const float4*)bg1)[id - 256];
      ((float4*)bqg1)[id] = v;
    }
    return;
  }
  {                                       // --- Ws transpose -> bf16 ---
    int f = bx - 11785;                   // 0..495
    int kt = f % 31, ct = f / 31;
    const float* Ws; int kb, scj, offj;
    if (kt < 1)       { Ws = Ws0; kb = kt;      scj = 64;   offj = 0;   }
    else if (kt < 3)  { Ws = Ws1; kb = kt - 1;  scj = 128;  offj = 64;  }
    else if (kt < 7)  { Ws = Ws2; kb = kt - 3;  scj = 256;  offj = 192; }
    else if (kt < 15) { Ws = Ws3; kb = kt - 7;  scj = 512;  offj = 448; }
    else              { Ws = Ws4; kb = kt - 15; scj = 1024; offj = 960; }
    int c0 = ct << 6, k0 = kb << 6;
    int col = t & 63, r4 = t >> 6;
#pragma unroll
    for (int p = 0; p < 16; ++p) {
      int r = (p << 2) + r4;
      tile[r][col] = Ws[(size_t)(c0 + r) * scj + k0 + col];
    }
    __syncthreads();
#pragma unroll
    for (int p = 0; p < 16; ++p) {
      int r = (p << 2) + r4;
      WsT[(size_t)(offj + k0 + r) * 1024 + c0 + col] = f2b(tile[col][r]);
    }
  }
}

// ---------------- fused attn-reduction + gate + softmax -> aw --------------
__global__ __launch_bounds__(256) void attn_gate_kernel(
    const ushort* __restrict__ QH, const ushort* __restrict__ KV,
    const int* __restrict__ routes, const float* __restrict__ temp,
    const float* __restrict__ g_gamma, const float* __restrict__ g_beta,
    const float* __restrict__ Wg2, const float* __restrict__ bg2,
    float* __restrict__ aw)
{
  const int wave = threadIdx.x >> 6, lane = threadIdx.x & 63;
  const int b = (blockIdx.x << 2) + wave;
  const ushort* q = QH + (size_t)b * 1536 + (lane << 4);
  const ushort* kv = KV + (size_t)b * 10240 + (lane << 4);

  float qv[16];
  {
    u16x8 q0 = ((const u16x8*)q)[0];
    u16x8 q1 = ((const u16x8*)q)[1];
#pragma unroll
    for (int t = 0; t < 8; ++t) { qv[t] = b2f(q0[t]); qv[8 + t] = b2f(q1[t]); }
  }
  float vv[5][16];
  float p[20];
#pragma unroll
  for (int j = 0; j < 5; ++j) {
    u16x8 k0 = ((const u16x8*)(kv + j * 2048))[0];
    u16x8 k1 = ((const u16x8*)(kv + j * 2048))[1];
    u16x8 v0 = ((const u16x8*)(kv + j * 2048 + 1024))[0];
    u16x8 v1 = ((const u16x8*)(kv + j * 2048 + 1024))[1];
    float s = 0.f;
#pragma unroll
    for (int t = 0; t < 8; ++t) {
      s += qv[t] * b2f(k0[t]) + qv[8 + t] * b2f(k1[t]);
      vv[j][t] = b2f(v0[t]); vv[j][8 + t] = b2f(v1[t]);
    }
    p[j] = s;
  }
  {
    int idx = 5;
#pragma unroll
    for (int a = 0; a < 5; ++a)
#pragma unroll
      for (int c2 = a; c2 < 5; ++c2) {
        float s = 0.f;
#pragma unroll
        for (int t = 0; t < 16; ++t) s += vv[a][t] * vv[c2][t];
        p[idx++] = s;
      }
  }
#pragma unroll
  for (int t = 0; t < 20; ++t) {
    p[t] += __shfl_xor(p[t], 1, 64);
    p[t] += __shfl_xor(p[t], 2, 64);
  }
  float inv = 1.0f / (8.0f * fabsf(temp[0]));   // /sqrt(D) /|temperature|
  float si5[5];
#pragma unroll
  for (int s = 0; s < 5; ++s) {
    int r0 = routes[s * 3 + 0], r1 = routes[s * 3 + 1], r2 = routes[s * 3 + 2];
    float x0 = p[r0] * inv, x1 = p[r1] * inv, x2 = p[r2] * inv;
    float mx = fmaxf(x0, fmaxf(x1, x2));
    float e0 = __expf(x0 - mx), e1 = __expf(x1 - mx), e2 = __expf(x2 - mx);
    float den = e0 + e1 + e2;
    float a0 = e0 / den, a1 = e1 / den, a2 = e2 / den;
    auto G = [&](int i, int j2) -> float {
      int a = i < j2 ? i : j2, bb = i < j2 ? j2 : i;
      return p[5 + 5 * a - ((a * (a - 1)) >> 1) + (bb - a)];
    };
    float val = a0 * a0 * G(r0, r0) + a1 * a1 * G(r1, r1) + a2 * a2 * G(r2, r2)
              + 2.f * (a0 * a1 * G(r0, r1) + a0 * a2 * G(r0, r2) + a1 * a2 * G(r1, r2));
    float o = sqrtf(fmaxf(val, 0.f));
    // head-mean: butterfly over lane bits 2..5 sums one value per head -> /16
    o += __shfl_xor(o, 4, 64);  o += __shfl_xor(o, 8, 64);
    o += __shfl_xor(o, 16, 64); o += __shfl_xor(o, 32, 64);
    si5[s] = o * (1.f / 16.f);
  }

  const ushort* hr = QH + (size_t)b * 1536 + 1024 + (lane << 3);
  float hv[8], s1 = 0.f, s2 = 0.f;
  {
    u16x8 h8 = *(const u16x8*)hr;
#pragma unroll
    for (int t = 0; t < 8; ++t) {
      float x = b2f(h8[t]);
      hv[t] = x; s1 += x; s2 += x * x;
    }
  }
#pragma unroll
  for (int m = 1; m < 64; m <<= 1) {
    s1 += __shfl_xor(s1, m, 64);
    s2 += __shfl_xor(s2, m, 64);
  }
  float mean = s1 * (1.f / 512.f);
  float var = s2 * (1.f / 512.f) - mean * mean;     // population var (ddof=0)
  float rstd = rsqrtf(var + 1e-5f);
  float4 gg0 = ((const float4*)(g_gamma + (lane << 3)))[0];
  float4 gg1 = ((const float4*)(g_gamma + (lane << 3)))[1];
  float4 gb0 = ((const float4*)(g_beta + (lane << 3)))[0];
  float4 gb1 = ((const float4*)(g_beta + (lane << 3)))[1];
  float gam[8] = {gg0.x, gg0.y, gg0.z, gg0.w, gg1.x, gg1.y, gg1.z, gg1.w};
  float bet[8] = {gb0.x, gb0.y, gb0.z, gb0.w, gb1.x, gb1.y, gb1.z, gb1.w};
  float gel[8];
#pragma unroll
  for (int t = 0; t < 8; ++t) {
    float x = (hv[t] - mean) * rstd * gam[t] + bet[t];
    gel[t] = 0.5f * x * (1.f + erff(x * 0.70710678118654752f));  // exact gelu
  }
  float acc5[5];
#pragma unroll
  for (int s = 0; s < 5; ++s) {
    const float* wr = Wg2 + s * 512 + (lane << 3);
    float4 w0 = ((const float4*)wr)[0];
    float4 w1 = ((const float4*)wr)[1];
    float a = gel[0] * w0.x + gel[1] * w0.y + gel[2] * w0.z + gel[3] * w0.w
            + gel[4] * w1.x + gel[5] * w1.y + gel[6] * w1.z + gel[7] * w1.w;
#pragma unroll
    for (int m = 1; m < 64; m <<= 1) a += __shfl_xor(a, m, 64);
    acc5[s] = a;
  }
  if (lane == 0) {
    float cs[5];
#pragma unroll
    for (int s = 0; s < 5; ++s)
      cs[s] = 0.7f * si5[s] + 0.3f * (acc5[s] + bg2[s]);
    float mx = cs[0];
#pragma unroll
    for (int s = 1; s < 5; ++s) mx = fmaxf(mx, cs[s]);
    float e[5], sum = 0.f;
#pragma unroll
    for (int s = 0; s < 5; ++s) { e[s] = __expf(cs[s] - mx); sum += e[s]; }
    float rs = 1.f / sum;
#pragma unroll
    for (int s = 0; s < 5; ++s) aw[(size_t)b * 5 + s] = e[s] * rs;
  }
}

// ---------------- final: combined_logits = sum_s aw_s * logits_s -----------
__global__ __launch_bounds__(256) void combine_kernel(
    const float* __restrict__ aw,
    const float* __restrict__ l0, const float* __restrict__ l1,
    const float* __restrict__ l2, const float* __restrict__ l3,
    const float* __restrict__ l4, float* __restrict__ out)
{
  int b = blockIdx.x, t = threadIdx.x;
  float a0 = aw[(size_t)b * 5 + 0], a1 = aw[(size_t)b * 5 + 1],
        a2 = aw[(size_t)b * 5 + 2], a3 = aw[(size_t)b * 5 + 3],
        a4 = aw[(size_t)b * 5 + 4];
  if (t < 250) {
    size_t base = (size_t)b * 250 + t;
    float4 x0 = ((const float4*)l0)[base];
    float4 x1 = ((const float4*)l1)[base];
    float4 x2 = ((const float4*)l2)[base];
    float4 x3 = ((const float4*)l3)[base];
    float4 x4 = ((const float4*)l4)[base];
    float4 r;
    r.x = a0 * x0.x + a1 * x1.x + a2 * x2.x + a3 * x3.x + a4 * x4.x;
    r.y = a0 * x0.y + a1 * x1.y + a2 * x2.y + a3 * x3.y + a4 * x4.y;
    r.z = a0 * x0.z + a1 * x1.z + a2 * x2.z + a3 * x3.z + a4 * x4.z;
    r.w = a0 * x0.w + a1 * x1.w + a2 * x2.w + a3 * x3.w + a4 * x4.w;
    ((float4*)out)[base] = r;
  }
}

// ---------------------------------------------------------------------------
extern "C" void kernel_launch(void* const* d_in, const int* in_sizes, int n_in,
                              void* d_out, int out_size, void* d_ws, size_t ws_size,
                              hipStream_t stream) {
  const float* features = (const float*)d_in[0];
  const float* sf0 = (const float*)d_in[1];
  const float* sf1 = (const float*)d_in[2];
  const float* sf2 = (const float*)d_in[3];
  const float* sf3 = (const float*)d_in[4];
  const float* sf4 = (const float*)d_in[5];
  const float* lg0 = (const float*)d_in[6];
  const float* lg1 = (const float*)d_in[7];
  const float* lg2 = (const float*)d_in[8];
  const float* lg3 = (const float*)d_in[9];
  const float* lg4 = (const float*)d_in[10];
  const float* Ws0 = (const float*)d_in[11];
  const float* Ws1 = (const float*)d_in[12];
  const float* Ws2 = (const float*)d_in[13];
  const float* Ws3 = (const float*)d_in[14];
  const float* Ws4 = (const float*)d_in[15];
  const float* bs   = (const float*)d_in[16];
  const float* semb = (const float*)d_in[17];
  const float* Wq  = (const float*)d_in[18];
  const float* bq  = (const float*)d_in[19];
  const float* Wk  = (const float*)d_in[20];
  const float* bk  = (const float*)d_in[21];
  const float* Wv  = (const float*)d_in[22];
  const float* bv  = (const float*)d_in[23];
  const float* Wg1 = (const float*)d_in[24];
  const float* bg1 = (const float*)d_in[25];
  const float* g_gamma = (const float*)d_in[26];
  const float* g_beta  = (const float*)d_in[27];
  const float* Wg2 = (const float*)d_in[28];
  const float* bg2 = (const float*)d_in[29];
  const float* temp = (const float*)d_in[30];
  const int* routes = (const int*)d_in[31];

  // workspace layout
  char* w = (char*)d_ws;
  ushort* sfc   = (ushort*)w;                 w += 8192ull * 1984 * 2;
  ushort* featb = (ushort*)w;                 w += 8192ull * 1024 * 2;
  ushort* Wqh   = (ushort*)w;                 w += 1536ull * 1024 * 2;   // [Wq;Wg1]
  ushort* WsT   = (ushort*)w;                 w += 1984ull * 1024 * 2;
  ushort* Akv   = (ushort*)w;                 w += 2048ull * 1984 * 2;   // [Wk;Wv]@Ws
  ushort* Wkvb  = (ushort*)w;                 w += 2048ull * 1024 * 2;
  ushort* bse   = (ushort*)w;                 w += 5ull * 1024 * 2 + 256 - (5ull*1024*2)%256;
  float*  bkv   = (float*)w;                  w += 2048ull * 4;
  float*  bqg1  = (float*)w;                  w += 1536ull * 4;
  float*  ckv   = (float*)w;                  w += 5ull * 2048 * 4;
  float*  si_unused = (float*)w;              w += 8192ull * 5 * 4;
  ushort* QH    = (ushort*)w;                 w += 8192ull * 1536 * 2;   // [Q|h]
  ushort* KV    = (ushort*)w;                 w += 8192ull * 10240 * 2;
  (void)si_unused;

  float* out = (float*)d_out;
  float* aw = out + 8192ull * 1000;

  static const int offj[5] = {0, 64, 192, 448, 960};
  static const int scj[5]  = {64, 128, 256, 512, 1024};

  // 1) all prep in one launch
  prep_all<<<12281, 256, 0, stream>>>(
      features, sf0, sf1, sf2, sf3, sf4,
      Wq, Wg1, Wk, Wv, bs, semb, bk, bv, bq, bg1,
      Ws0, Ws1, Ws2, Ws3, Ws4,
      featb, sfc, Wqh, Wkvb, bse, bkv, bqg1, WsT);

  // 2) Akv = [Wk;Wv] @ Ws_cat   (M=2048, N=1984, K=1024) -> bf16
  gemm_xwt<<<dim3(16, 16), 256, 0, stream>>>(Wkvb, 1024, WsT, 1024,
                                             Akv, 1984, 2048, 1984, 1024);
  // 3) ckv[s][n] (5x2048 dots)
  ckv_kernel<<<2560, 256, 0, stream>>>(bse, Wkvb, bkv, ckv);

  // 4) mega GEMM: 5 KV jobs + QH job in one dispatch
  GemmJobs jobs;
  for (int j = 0; j < 5; ++j) {
    jobs.j[j].X = sfc + offj[j];  jobs.j[j].ldx = 1984;
    jobs.j[j].W = Akv + offj[j];  jobs.j[j].ldw = 1984;
    jobs.j[j].C = KV + j * 2048;  jobs.j[j].ldo = 10240;
    jobs.j[j].bias = ckv + (size_t)j * 2048;
    jobs.j[j].K = scj[j];  jobs.j[j].N = 2048;  jobs.j[j].pad = 0;
  }
  jobs.j[5].X = featb;  jobs.j[5].ldx = 1024;
  jobs.j[5].W = Wqh;    jobs.j[5].ldw = 1024;
  jobs.j[5].C = QH;     jobs.j[5].ldo = 1536;
  jobs.j[5].bias = bqg1;
  jobs.j[5].K = 1024;   jobs.j[5].N = 1536;  jobs.j[5].pad = 0;
  mega_gemm<<<dim3(64, 16, 6), 256, 0, stream>>>(jobs);

  // 5) attention + gate -> aw
  attn_gate_kernel<<<2048, 256, 0, stream>>>(QH, KV, routes, temp,
                                             g_gamma, g_beta, Wg2, bg2, aw);
  // 6) combine logits
  combine_kernel<<<8192, 256, 0, stream>>>(aw, lg0, lg1, lg2, lg3, lg4, out);

  (void)in_sizes; (void)n_in; (void)out_size; (void)ws_size;
}